// Round 1
// baseline (5800.907 us; speedup 1.0000x reference)
//
#include <hip/hip_runtime.h>

#define N_NODES   100000
#define N_EDGES   1600000
#define NFEAT     128
#define NGRAPHS   2048

// ---------------- utility fills ----------------
__global__ void k_fill(float* __restrict__ p, float v, int n) {
    int i = blockIdx.x * blockDim.x + threadIdx.x;
    if (i < n) p[i] = v;
}

// deg[dst] += 1 per edge (deg pre-filled with 1.0 for the self-loop)
__global__ void k_degree(const int* __restrict__ dst, float* __restrict__ deg) {
    int e = blockIdx.x * blockDim.x + threadIdx.x;
    if (e < N_EDGES) atomicAdd(&deg[dst[e]], 1.0f);
}

// deg -> dinv = rsqrt(deg), in place
__global__ void k_rsqrt(float* __restrict__ d, int n) {
    int i = blockIdx.x * blockDim.x + threadIdx.x;
    if (i < n) d[i] = rsqrtf(d[i]);
}

// ---------------- GEMM: C[nrows,128] = X[nrows,128] @ W[128,128] ----------------
// 64x64 tile per block, 256 threads, each thread 4x4 micro-tile. K=128 fits in one LDS tile.
__global__ __launch_bounds__(256) void k_gemm128(const float* __restrict__ X,
                                                 const float* __restrict__ W,
                                                 float* __restrict__ C, int nrows) {
    __shared__ float Xs[64][132];   // +4 pad breaks bank aliasing
    __shared__ float Ws[128][68];
    const int tid = threadIdx.x;
    const int r0 = blockIdx.x * 64;
    const int c0 = blockIdx.y * 64;

    // load X tile: 64 rows x 128 cols
    {
        int row = tid >> 5;            // 0..7
        int q   = (tid & 31) * 4;      // 0..124
        for (int it = 0; it < 8; ++it) {
            int r  = row + it * 8;
            int gr = r0 + r;
            float4 v = make_float4(0.f, 0.f, 0.f, 0.f);
            if (gr < nrows) v = *(const float4*)(X + (size_t)gr * NFEAT + q);
            *(float4*)(&Xs[r][q]) = v;
        }
    }
    // load W tile: 128 rows x 64 cols (offset c0)
    {
        int row = tid >> 4;            // 0..15
        int q   = (tid & 15) * 4;      // 0..60
        for (int it = 0; it < 8; ++it) {
            int k = row + it * 16;
            float4 v = *(const float4*)(W + (size_t)k * NFEAT + c0 + q);
            *(float4*)(&Ws[k][q]) = v;
        }
    }
    __syncthreads();

    const int tr = (tid >> 4) * 4;   // 0..60
    const int tc = (tid & 15) * 4;   // 0..60
    float acc[4][4] = {};
    for (int k = 0; k < 128; k += 4) {
        float xs[4][4], ws[4][4];
        for (int i = 0; i < 4; ++i) {
            float4 t = *(const float4*)(&Xs[tr + i][k]);
            xs[i][0] = t.x; xs[i][1] = t.y; xs[i][2] = t.z; xs[i][3] = t.w;
        }
        for (int j = 0; j < 4; ++j) {
            float4 t = *(const float4*)(&Ws[k + j][tc]);
            ws[j][0] = t.x; ws[j][1] = t.y; ws[j][2] = t.z; ws[j][3] = t.w;
        }
        for (int i = 0; i < 4; ++i)
            for (int j = 0; j < 4; ++j)
                for (int c = 0; c < 4; ++c)
                    acc[i][c] += xs[i][j] * ws[j][c];
    }

    for (int i = 0; i < 4; ++i) {
        int gr = r0 + tr + i;
        if (gr < nrows) {
            float4 v = make_float4(acc[i][0], acc[i][1], acc[i][2], acc[i][3]);
            *(float4*)(C + (size_t)gr * NFEAT + c0 + tc) = v;
        }
    }
}

// ---------------- edge scatter: agg[dst] += xw[src] * dinv[src]*dinv[dst] ----------------
// 32 lanes per edge, 4 floats per lane.
__global__ __launch_bounds__(256) void k_scatter(const float* __restrict__ xw,
                                                  const int* __restrict__ src,
                                                  const int* __restrict__ dst,
                                                  const float* __restrict__ dinv,
                                                  float* __restrict__ agg) {
    long long t = (long long)blockIdx.x * blockDim.x + threadIdx.x;
    int e = (int)(t >> 5);
    int l = (int)(t & 31);
    if (e >= N_EDGES) return;
    int s = src[e], d = dst[e];
    float nrm = dinv[s] * dinv[d];
    float4 v = *(const float4*)(xw + (size_t)s * NFEAT + l * 4);
    float* ap = agg + (size_t)d * NFEAT + l * 4;
    atomicAdd(ap + 0, v.x * nrm);
    atomicAdd(ap + 1, v.y * nrm);
    atomicAdd(ap + 2, v.z * nrm);
    atomicAdd(ap + 3, v.w * nrm);
}

// ---------------- epilogue: out = [relu](agg + xw*dinv^2 + b) ----------------
__global__ void k_epilogue(const float* __restrict__ agg, const float* __restrict__ xw,
                           const float* __restrict__ dinv, const float* __restrict__ b,
                           float* __restrict__ out, int do_relu) {
    int i = blockIdx.x * blockDim.x + threadIdx.x;   // over N*128/4 float4s
    if (i >= N_NODES * (NFEAT / 4)) return;
    int node = i >> 5;           // i/32
    int f    = (i & 31) * 4;
    float dv = dinv[node];
    float id = dv * dv;
    float4 a  = ((const float4*)agg)[i];
    float4 x  = ((const float4*)xw)[i];
    float4 bb = *(const float4*)(b + f);
    float4 r;
    r.x = a.x + x.x * id + bb.x;
    r.y = a.y + x.y * id + bb.y;
    r.z = a.z + x.z * id + bb.z;
    r.w = a.w + x.w * id + bb.w;
    if (do_relu) {
        r.x = fmaxf(r.x, 0.f); r.y = fmaxf(r.y, 0.f);
        r.z = fmaxf(r.z, 0.f); r.w = fmaxf(r.w, 0.f);
    }
    ((float4*)out)[i] = r;
}

// ---------------- per-graph node count ----------------
__global__ void k_count(const int* __restrict__ batch, float* __restrict__ gcnt) {
    int i = blockIdx.x * blockDim.x + threadIdx.x;
    if (i < N_NODES) atomicAdd(&gcnt[batch[i]], 1.0f);
}

// ---------------- fused (h2 . Wlin) + segment-sum into graphs ----------------
// one 64-lane wave per node; each lane covers 2 features.
__global__ __launch_bounds__(256) void k_pool(const float* __restrict__ h2,
                                               const int* __restrict__ batch,
                                               const float* __restrict__ Wlin,
                                               float* __restrict__ gsum) {
    long long t = (long long)blockIdx.x * blockDim.x + threadIdx.x;
    int node = (int)(t >> 6);
    int l    = (int)(t & 63);
    if (node >= N_NODES) return;
    const float* hp = h2 + (size_t)node * NFEAT;
    float p = hp[l] * Wlin[l] + hp[64 + l] * Wlin[64 + l];
    for (int off = 32; off > 0; off >>= 1) p += __shfl_down(p, off);
    if (l == 0) atomicAdd(&gsum[batch[node]], p);
}

// ---------------- final: out[g] = gsum/max(cnt,1) + blin ----------------
__global__ void k_final(const float* __restrict__ gsum, const float* __restrict__ gcnt,
                        const float* __restrict__ blin, float* __restrict__ out) {
    int g = blockIdx.x * blockDim.x + threadIdx.x;
    if (g < NGRAPHS) out[g] = gsum[g] / fmaxf(gcnt[g], 1.0f) + blin[0];
}

extern "C" void kernel_launch(void* const* d_in, const int* in_sizes, int n_in,
                              void* d_out, int out_size, void* d_ws, size_t ws_size,
                              hipStream_t stream) {
    const float* x    = (const float*)d_in[0];
    const int*   ei   = (const int*)d_in[1];      // [2, E] flat: src = ei[0:E), dst = ei[E:2E)
    const int*   bat  = (const int*)d_in[2];
    const float* W1   = (const float*)d_in[3];
    const float* b1   = (const float*)d_in[4];
    const float* W2   = (const float*)d_in[5];
    const float* b2   = (const float*)d_in[6];
    const float* Wlin = (const float*)d_in[7];
    const float* blin = (const float*)d_in[8];
    float* out = (float*)d_out;

    const int* src = ei;
    const int* dst = ei + N_EDGES;

    // workspace layout (floats)
    const size_t NF = (size_t)N_NODES * NFEAT;   // 12.8M
    float* bufA = (float*)d_ws;                  // xw
    float* bufB = bufA + NF;                     // agg / h
    float* deg  = bufB + NF;                     // deg -> dinv (in place)
    float* gsum = deg + N_NODES;
    float* gcnt = gsum + NGRAPHS;

    const int BS = 256;
    dim3 gemm_grid((N_NODES + 63) / 64, 2);
    int scat_blocks = (int)(((long long)N_EDGES * 32 + BS - 1) / BS);
    int epi_blocks  = (N_NODES * (NFEAT / 4) + BS - 1) / BS;
    int pool_blocks = (int)(((long long)N_NODES * 64 + BS - 1) / BS);

    // ---- degree / norms (shared by both layers) ----
    k_fill<<<(N_NODES + BS - 1) / BS, BS, 0, stream>>>(deg, 1.0f, N_NODES);
    hipMemsetAsync(gsum, 0, (NGRAPHS * 2) * sizeof(float), stream);   // gsum + gcnt
    k_degree<<<(N_EDGES + BS - 1) / BS, BS, 0, stream>>>(dst, deg);
    k_rsqrt<<<(N_NODES + BS - 1) / BS, BS, 0, stream>>>(deg, N_NODES);
    const float* dinv = deg;

    // ---- layer 1 ----
    hipMemsetAsync(bufB, 0, NF * sizeof(float), stream);                 // agg1 = 0
    k_gemm128<<<gemm_grid, BS, 0, stream>>>(x, W1, bufA, N_NODES);       // xw1
    k_scatter<<<scat_blocks, BS, 0, stream>>>(bufA, src, dst, dinv, bufB);
    k_epilogue<<<epi_blocks, BS, 0, stream>>>(bufB, bufA, dinv, b1, bufB, 1);  // h1 in bufB

    // ---- layer 2 ----
    k_gemm128<<<gemm_grid, BS, 0, stream>>>(bufB, W2, bufA, N_NODES);    // xw2 in bufA
    hipMemsetAsync(bufB, 0, NF * sizeof(float), stream);                 // agg2 = 0 (h1 dead)
    k_scatter<<<scat_blocks, BS, 0, stream>>>(bufA, src, dst, dinv, bufB);
    k_epilogue<<<epi_blocks, BS, 0, stream>>>(bufB, bufA, dinv, b2, bufB, 0);  // h2 in bufB

    // ---- pool + linear ----
    k_count<<<(N_NODES + BS - 1) / BS, BS, 0, stream>>>(bat, gcnt);
    k_pool<<<pool_blocks, BS, 0, stream>>>(bufB, bat, Wlin, gsum);
    k_final<<<(NGRAPHS + BS - 1) / BS, BS, 0, stream>>>(gsum, gcnt, blin, out);
}

// Round 2
// 719.251 us; speedup vs baseline: 8.0652x; 8.0652x over previous
//
#include <hip/hip_runtime.h>

#define N_NODES   100000
#define N_EDGES   1600000
#define NFEAT     128
#define NGRAPHS   2048
#define SCAN_CHUNK 1024   // elements per scan block (256 thr x 4)

// ---------------- degree histogram (int) ----------------
__global__ void k_hist(const int* __restrict__ dst, int* __restrict__ indeg) {
    int e = blockIdx.x * blockDim.x + threadIdx.x;
    if (e < N_EDGES) atomicAdd(&indeg[dst[e]], 1);
}

// dinv = rsqrt(indeg + 1)   (self loop included)
__global__ void k_dinv(const int* __restrict__ indeg, float* __restrict__ dinv) {
    int i = blockIdx.x * blockDim.x + threadIdx.x;
    if (i < N_NODES) dinv[i] = rsqrtf((float)indeg[i] + 1.0f);
}

// ---------------- 3-kernel exclusive scan of indeg -> row_start ----------------
__global__ __launch_bounds__(256) void k_scan1(const int* __restrict__ in,
                                               int* __restrict__ out,
                                               int* __restrict__ bsum, int n) {
    __shared__ int sdata[256];
    const int t = threadIdx.x;
    const int base = blockIdx.x * SCAN_CHUNK + t * 4;
    int v[4];
    for (int i = 0; i < 4; ++i) v[i] = (base + i < n) ? in[base + i] : 0;
    int local = v[0] + v[1] + v[2] + v[3];
    sdata[t] = local;
    __syncthreads();
    for (int off = 1; off < 256; off <<= 1) {
        int x = (t >= off) ? sdata[t - off] : 0;
        __syncthreads();
        sdata[t] += x;
        __syncthreads();
    }
    int excl = sdata[t] - local;
    if (t == 255) bsum[blockIdx.x] = sdata[255];
    int run = excl;
    for (int i = 0; i < 4; ++i) {
        if (base + i < n) out[base + i] = run;
        run += v[i];
    }
}

__global__ __launch_bounds__(128) void k_scan2(int* __restrict__ bsum, int nb) {
    __shared__ int sdata[128];
    const int t = threadIdx.x;
    int v = (t < nb) ? bsum[t] : 0;
    sdata[t] = v;
    __syncthreads();
    for (int off = 1; off < 128; off <<= 1) {
        int x = (t >= off) ? sdata[t - off] : 0;
        __syncthreads();
        sdata[t] += x;
        __syncthreads();
    }
    if (t < nb) bsum[t] = sdata[t] - v;   // exclusive
}

__global__ void k_scan3(int* __restrict__ out, const int* __restrict__ bsum, int n) {
    int i = blockIdx.x * blockDim.x + threadIdx.x;
    if (i < n) out[i] += bsum[i / SCAN_CHUNK];
}

// ---------------- CSR fill: csr_src[row_start[d] + cursor[d]++] = src[e] ----------------
__global__ void k_csr(const int* __restrict__ src, const int* __restrict__ dst,
                      const int* __restrict__ row_start, int* __restrict__ cursor,
                      int* __restrict__ csr_src) {
    int e = blockIdx.x * blockDim.x + threadIdx.x;
    if (e >= N_EDGES) return;
    int d = dst[e];
    int pos = row_start[d] + atomicAdd(&cursor[d], 1);
    csr_src[pos] = src[e];
}

// ---------------- GEMM: C[r,:] = (X[r,:] @ W) * dinv[r] ----------------
// 64x64 tile per block, 256 threads, 4x4 micro-tile. K=128 in one LDS tile.
__global__ __launch_bounds__(256) void k_gemm128(const float* __restrict__ X,
                                                 const float* __restrict__ W,
                                                 const float* __restrict__ dinv,
                                                 float* __restrict__ C, int nrows) {
    __shared__ float Xs[64][132];
    __shared__ float Ws[128][68];
    const int tid = threadIdx.x;
    const int r0 = blockIdx.x * 64;
    const int c0 = blockIdx.y * 64;

    {
        int row = tid >> 5;
        int q   = (tid & 31) * 4;
        for (int it = 0; it < 8; ++it) {
            int r  = row + it * 8;
            int gr = r0 + r;
            float4 v = make_float4(0.f, 0.f, 0.f, 0.f);
            if (gr < nrows) v = *(const float4*)(X + (size_t)gr * NFEAT + q);
            *(float4*)(&Xs[r][q]) = v;
        }
    }
    {
        int row = tid >> 4;
        int q   = (tid & 15) * 4;
        for (int it = 0; it < 8; ++it) {
            int k = row + it * 16;
            float4 v = *(const float4*)(W + (size_t)k * NFEAT + c0 + q);
            *(float4*)(&Ws[k][q]) = v;
        }
    }
    __syncthreads();

    const int tr = (tid >> 4) * 4;
    const int tc = (tid & 15) * 4;
    float acc[4][4] = {};
    for (int k = 0; k < 128; k += 4) {
        float xs[4][4], ws[4][4];
        for (int i = 0; i < 4; ++i) {
            float4 t = *(const float4*)(&Xs[tr + i][k]);
            xs[i][0] = t.x; xs[i][1] = t.y; xs[i][2] = t.z; xs[i][3] = t.w;
        }
        for (int j = 0; j < 4; ++j) {
            float4 t = *(const float4*)(&Ws[k + j][tc]);
            ws[j][0] = t.x; ws[j][1] = t.y; ws[j][2] = t.z; ws[j][3] = t.w;
        }
        for (int i = 0; i < 4; ++i)
            for (int j = 0; j < 4; ++j)
                for (int c = 0; c < 4; ++c)
                    acc[i][c] += xs[i][j] * ws[j][c];
    }

    for (int i = 0; i < 4; ++i) {
        int gr = r0 + tr + i;
        if (gr < nrows) {
            float s = dinv[gr];     // fold D^{-1/2} of the row into xw
            float4 v = make_float4(acc[i][0] * s, acc[i][1] * s, acc[i][2] * s, acc[i][3] * s);
            *(float4*)(C + (size_t)gr * NFEAT + c0 + tc) = v;
        }
    }
}

// ---------------- gather-aggregate + fused epilogue ----------------
// xws rows are pre-scaled by dinv[row]. One 64-lane wave per dst node, float2/lane.
// out[d] = relu?( dinv[d] * ( sum_{s in N(d)} xws[s] + xws[d] ) + b )
__global__ __launch_bounds__(256) void k_gather(const float* __restrict__ xws,
                                                const int* __restrict__ csr_src,
                                                const int* __restrict__ row_start,
                                                const int* __restrict__ indeg,
                                                const float* __restrict__ dinv,
                                                const float* __restrict__ b,
                                                float* __restrict__ out, int do_relu) {
    long long t = (long long)blockIdx.x * blockDim.x + threadIdx.x;
    int node = (int)(t >> 6);
    int l    = (int)(t & 63);
    if (node >= N_NODES) return;
    const int beg = row_start[node];
    const int cnt = indeg[node];
    float ax = 0.f, ay = 0.f;
    int j = 0;
    #pragma unroll 1
    for (; j + 4 <= cnt; j += 4) {
        int s0 = csr_src[beg + j + 0];
        int s1 = csr_src[beg + j + 1];
        int s2 = csr_src[beg + j + 2];
        int s3 = csr_src[beg + j + 3];
        float2 v0 = *(const float2*)(xws + (size_t)s0 * NFEAT + l * 2);
        float2 v1 = *(const float2*)(xws + (size_t)s1 * NFEAT + l * 2);
        float2 v2 = *(const float2*)(xws + (size_t)s2 * NFEAT + l * 2);
        float2 v3 = *(const float2*)(xws + (size_t)s3 * NFEAT + l * 2);
        ax += v0.x + v1.x + v2.x + v3.x;
        ay += v0.y + v1.y + v2.y + v3.y;
    }
    for (; j < cnt; ++j) {
        int s = csr_src[beg + j];
        float2 v = *(const float2*)(xws + (size_t)s * NFEAT + l * 2);
        ax += v.x; ay += v.y;
    }
    // self loop (xws[node] already carries one dinv factor)
    float2 xv = *(const float2*)(xws + (size_t)node * NFEAT + l * 2);
    ax += xv.x; ay += xv.y;
    float dv = dinv[node];
    float bx = b[l * 2], by = b[l * 2 + 1];
    float rx = ax * dv + bx;
    float ry = ay * dv + by;
    if (do_relu) { rx = fmaxf(rx, 0.f); ry = fmaxf(ry, 0.f); }
    *(float2*)(out + (size_t)node * NFEAT + l * 2) = make_float2(rx, ry);
}

// ---------------- per-graph node count ----------------
__global__ void k_count(const int* __restrict__ batch, float* __restrict__ gcnt) {
    int i = blockIdx.x * blockDim.x + threadIdx.x;
    if (i < N_NODES) atomicAdd(&gcnt[batch[i]], 1.0f);
}

// ---------------- fused (h2 . Wlin) + segment-sum into graphs ----------------
__global__ __launch_bounds__(256) void k_pool(const float* __restrict__ h2,
                                               const int* __restrict__ batch,
                                               const float* __restrict__ Wlin,
                                               float* __restrict__ gsum) {
    long long t = (long long)blockIdx.x * blockDim.x + threadIdx.x;
    int node = (int)(t >> 6);
    int l    = (int)(t & 63);
    if (node >= N_NODES) return;
    const float* hp = h2 + (size_t)node * NFEAT;
    float p = hp[l] * Wlin[l] + hp[64 + l] * Wlin[64 + l];
    for (int off = 32; off > 0; off >>= 1) p += __shfl_down(p, off);
    if (l == 0) atomicAdd(&gsum[batch[node]], p);
}

__global__ void k_final(const float* __restrict__ gsum, const float* __restrict__ gcnt,
                        const float* __restrict__ blin, float* __restrict__ out) {
    int g = blockIdx.x * blockDim.x + threadIdx.x;
    if (g < NGRAPHS) out[g] = gsum[g] / fmaxf(gcnt[g], 1.0f) + blin[0];
}

extern "C" void kernel_launch(void* const* d_in, const int* in_sizes, int n_in,
                              void* d_out, int out_size, void* d_ws, size_t ws_size,
                              hipStream_t stream) {
    const float* x    = (const float*)d_in[0];
    const int*   ei   = (const int*)d_in[1];
    const int*   bat  = (const int*)d_in[2];
    const float* W1   = (const float*)d_in[3];
    const float* b1   = (const float*)d_in[4];
    const float* W2   = (const float*)d_in[5];
    const float* b2   = (const float*)d_in[6];
    const float* Wlin = (const float*)d_in[7];
    const float* blin = (const float*)d_in[8];
    float* out = (float*)d_out;

    const int* src = ei;
    const int* dst = ei + N_EDGES;

    // ---- workspace layout ----
    const size_t NF = (size_t)N_NODES * NFEAT;        // 12.8M floats
    float* bufA = (float*)d_ws;                        // xw (scaled)
    float* bufB = bufA + NF;                           // h
    float* dinv = bufB + NF;                           // [N]
    float* gsum = dinv + N_NODES;                      // [G]  } zeroed together
    float* gcnt = gsum + NGRAPHS;                      // [G]  }
    int* indeg     = (int*)(gcnt + NGRAPHS);           // [N]  } zeroed together
    int* cursor    = indeg + N_NODES;                  // [N]  }
    int* row_start = cursor + N_NODES;                 // [N]
    int* bsum      = row_start + N_NODES;              // [128]
    int* csr_src   = bsum + 128;                       // [E]

    const int BS = 256;
    const int nb_scan = (N_NODES + SCAN_CHUNK - 1) / SCAN_CHUNK;   // 98
    dim3 gemm_grid((N_NODES + 63) / 64, 2);
    int node_blocks = (N_NODES + BS - 1) / BS;
    int edge_blocks = (N_EDGES + BS - 1) / BS;
    int wave_blocks = (int)(((long long)N_NODES * 64 + BS - 1) / BS);

    // ---- zero the accumulators (gsum,gcnt,indeg,cursor are contiguous) ----
    hipMemsetAsync(gsum, 0, (2 * NGRAPHS) * sizeof(float) + (2 * N_NODES) * sizeof(int), stream);

    // ---- degree, norms, CSR ----
    k_hist<<<edge_blocks, BS, 0, stream>>>(dst, indeg);
    k_dinv<<<node_blocks, BS, 0, stream>>>(indeg, dinv);
    k_scan1<<<nb_scan, BS, 0, stream>>>(indeg, row_start, bsum, N_NODES);
    k_scan2<<<1, 128, 0, stream>>>(bsum, nb_scan);
    k_scan3<<<node_blocks, BS, 0, stream>>>(row_start, bsum, N_NODES);
    k_csr<<<edge_blocks, BS, 0, stream>>>(src, dst, row_start, cursor, csr_src);

    // ---- layer 1 ----
    k_gemm128<<<gemm_grid, BS, 0, stream>>>(x, W1, dinv, bufA, N_NODES);
    k_gather<<<wave_blocks, BS, 0, stream>>>(bufA, csr_src, row_start, indeg, dinv, b1, bufB, 1);

    // ---- layer 2 ----
    k_gemm128<<<gemm_grid, BS, 0, stream>>>(bufB, W2, dinv, bufA, N_NODES);
    k_gather<<<wave_blocks, BS, 0, stream>>>(bufA, csr_src, row_start, indeg, dinv, b2, bufB, 0);

    // ---- pool + linear ----
    k_count<<<node_blocks, BS, 0, stream>>>(bat, gcnt);
    k_pool<<<wave_blocks, BS, 0, stream>>>(bufB, bat, Wlin, gsum);
    k_final<<<(NGRAPHS + BS - 1) / BS, BS, 0, stream>>>(gsum, gcnt, blin, out);
}

// Round 3
// 573.423 us; speedup vs baseline: 10.1163x; 1.2543x over previous
//
#include <hip/hip_runtime.h>

#define N_NODES   100000
#define N_EDGES   1600000
#define NFEAT     128
#define NGRAPHS   2048
#define SCAN_CHUNK 1024   // elements per scan block (256 thr x 4)

typedef __attribute__((ext_vector_type(8))) short short8;   // 8 bf16 = 4 VGPRs
typedef __attribute__((ext_vector_type(4))) float f32x4;

// RNE float -> bf16 (finite inputs)
__device__ __forceinline__ unsigned short f2bf(float f) {
    unsigned int u = __float_as_uint(f);
    u += 0x7FFFu + ((u >> 16) & 1u);
    return (unsigned short)(u >> 16);
}

// ---------------- degree histogram (int) ----------------
__global__ void k_hist(const int* __restrict__ dst, int* __restrict__ indeg) {
    int e = blockIdx.x * blockDim.x + threadIdx.x;
    if (e < N_EDGES) atomicAdd(&indeg[dst[e]], 1);
}

__global__ void k_dinv(const int* __restrict__ indeg, float* __restrict__ dinv) {
    int i = blockIdx.x * blockDim.x + threadIdx.x;
    if (i < N_NODES) dinv[i] = rsqrtf((float)indeg[i] + 1.0f);
}

// ---------------- 3-kernel exclusive scan ----------------
__global__ __launch_bounds__(256) void k_scan1(const int* __restrict__ in,
                                               int* __restrict__ out,
                                               int* __restrict__ bsum, int n) {
    __shared__ int sdata[256];
    const int t = threadIdx.x;
    const int base = blockIdx.x * SCAN_CHUNK + t * 4;
    int v[4];
    for (int i = 0; i < 4; ++i) v[i] = (base + i < n) ? in[base + i] : 0;
    int local = v[0] + v[1] + v[2] + v[3];
    sdata[t] = local;
    __syncthreads();
    for (int off = 1; off < 256; off <<= 1) {
        int x = (t >= off) ? sdata[t - off] : 0;
        __syncthreads();
        sdata[t] += x;
        __syncthreads();
    }
    int excl = sdata[t] - local;
    if (t == 255) bsum[blockIdx.x] = sdata[255];
    int run = excl;
    for (int i = 0; i < 4; ++i) {
        if (base + i < n) out[base + i] = run;
        run += v[i];
    }
}

__global__ __launch_bounds__(128) void k_scan2(int* __restrict__ bsum, int nb) {
    __shared__ int sdata[128];
    const int t = threadIdx.x;
    int v = (t < nb) ? bsum[t] : 0;
    sdata[t] = v;
    __syncthreads();
    for (int off = 1; off < 128; off <<= 1) {
        int x = (t >= off) ? sdata[t - off] : 0;
        __syncthreads();
        sdata[t] += x;
        __syncthreads();
    }
    if (t < nb) bsum[t] = sdata[t] - v;   // exclusive
}

__global__ void k_scan3(int* __restrict__ out, const int* __restrict__ bsum, int n) {
    int i = blockIdx.x * blockDim.x + threadIdx.x;
    if (i < n) out[i] += bsum[i / SCAN_CHUNK];
}

// ---------------- CSR fill ----------------
__global__ void k_csr(const int* __restrict__ src, const int* __restrict__ dst,
                      const int* __restrict__ row_start, int* __restrict__ cursor,
                      int* __restrict__ csr_src) {
    int e = blockIdx.x * blockDim.x + threadIdx.x;
    if (e >= N_EDGES) return;
    int d = dst[e];
    int pos = row_start[d] + atomicAdd(&cursor[d], 1);
    csr_src[pos] = src[e];
}

// ---------------- W prep: fp32 [k][n] -> bf16 transposed [n][k] ----------------
__global__ void k_prepw(const float* __restrict__ W1, const float* __restrict__ W2,
                        unsigned short* __restrict__ WT1, unsigned short* __restrict__ WT2) {
    const float* W = blockIdx.x ? W2 : W1;
    unsigned short* WT = blockIdx.x ? WT2 : WT1;
    for (int i = threadIdx.x; i < 128 * 128; i += blockDim.x) {
        int n = i >> 7, k = i & 127;
        WT[i] = f2bf(W[k * 128 + n]);
    }
}

// ---------------- MFMA GEMM: C[r,:] = bf16( (X[r,:] @ W) * dinv[r] ) ----------------
// 128 rows/block, 256 threads (4 waves), wave tile 32x128, mfma_f32_16x16x32_bf16.
// A layout: A[m=lane&15][k=quad*8+j]; B via W^T in LDS: B[k][n=lane&15], k=quad*8+j.
// C/D: col=lane&15, row=quad*4+reg.
template<bool SRC_BF16>
__global__ __launch_bounds__(256) void k_gemm_mfma(const void* __restrict__ Xv,
                                                   const unsigned short* __restrict__ WT,
                                                   const float* __restrict__ dinv,
                                                   unsigned short* __restrict__ C,
                                                   int nrows) {
    __shared__ unsigned short As[128][136];   // +8 pad: b128 rows stay 16B-aligned, 2-way banks
    __shared__ unsigned short Ws[128][136];   // Wt: [n][k]
    const int tid = threadIdx.x;
    const int R0 = blockIdx.x * 128;

    // stage A (2 threads per row, 64 cols each)
    {
        int r = tid >> 1;
        int h = (tid & 1) * 64;
        int gr = R0 + r;
        if (SRC_BF16) {
            const unsigned short* X = (const unsigned short*)Xv;
            for (int c = 0; c < 64; c += 8) {
                short8 v = {};
                if (gr < nrows) v = *(const short8*)(X + (size_t)gr * NFEAT + h + c);
                *(short8*)(&As[r][h + c]) = v;
            }
        } else {
            const float* X = (const float*)Xv;
            for (int c = 0; c < 64; c += 8) {
                short8 v = {};
                if (gr < nrows) {
                    float4 f0 = *(const float4*)(X + (size_t)gr * NFEAT + h + c);
                    float4 f1 = *(const float4*)(X + (size_t)gr * NFEAT + h + c + 4);
                    v[0] = (short)f2bf(f0.x); v[1] = (short)f2bf(f0.y);
                    v[2] = (short)f2bf(f0.z); v[3] = (short)f2bf(f0.w);
                    v[4] = (short)f2bf(f1.x); v[5] = (short)f2bf(f1.y);
                    v[6] = (short)f2bf(f1.z); v[7] = (short)f2bf(f1.w);
                }
                *(short8*)(&As[r][h + c]) = v;
            }
        }
    }
    // stage Wt (bf16 global, already transposed)
    {
        int n = tid >> 1;
        int h = (tid & 1) * 64;
        for (int c = 0; c < 64; c += 8) {
            *(short8*)(&Ws[n][h + c]) = *(const short8*)(WT + n * 128 + h + c);
        }
    }
    __syncthreads();

    const int wv   = tid >> 6;    // 0..3 -> rows wv*32..wv*32+31
    const int lane = tid & 63;
    const int m16  = lane & 15;
    const int quad = lane >> 4;   // 0..3

    f32x4 acc[2][8] = {};
    #pragma unroll
    for (int ks = 0; ks < 4; ++ks) {
        const int k0 = ks * 32 + quad * 8;
        short8 a0 = *(const short8*)(&As[wv * 32 + m16][k0]);
        short8 a1 = *(const short8*)(&As[wv * 32 + 16 + m16][k0]);
        short8 b[8];
        #pragma unroll
        for (int ct = 0; ct < 8; ++ct)
            b[ct] = *(const short8*)(&Ws[ct * 16 + m16][k0]);
        #pragma unroll
        for (int ct = 0; ct < 8; ++ct) {
            acc[0][ct] = __builtin_amdgcn_mfma_f32_16x16x32_bf16(a0, b[ct], acc[0][ct], 0, 0, 0);
            acc[1][ct] = __builtin_amdgcn_mfma_f32_16x16x32_bf16(a1, b[ct], acc[1][ct], 0, 0, 0);
        }
    }

    #pragma unroll
    for (int t = 0; t < 2; ++t) {
        int rbase = R0 + wv * 32 + t * 16 + quad * 4;
        #pragma unroll
        for (int reg = 0; reg < 4; ++reg) {
            int gr = rbase + reg;
            if (gr < nrows) {
                float dv = dinv[gr];
                #pragma unroll
                for (int ct = 0; ct < 8; ++ct)
                    C[(size_t)gr * NFEAT + ct * 16 + m16] = f2bf(acc[t][ct][reg] * dv);
            }
        }
    }
}

// ---------------- gather-aggregate (bf16 table) + fused epilogue ----------------
// xwb rows pre-scaled by dinv[row]. One 64-lane wave per node, one bf16x2 (uint) per lane.
// out[d] = relu?( dinv[d] * ( sum_{s in N(d)} xwb[s] + xwb[d] ) + b )
template<bool OUT_BF16>
__global__ __launch_bounds__(256) void k_gather(const unsigned short* __restrict__ xwb,
                                                const int* __restrict__ csr_src,
                                                const int* __restrict__ row_start,
                                                const int* __restrict__ indeg,
                                                const float* __restrict__ dinv,
                                                const float* __restrict__ b,
                                                void* __restrict__ outv, int do_relu) {
    long long t = (long long)blockIdx.x * blockDim.x + threadIdx.x;
    int node = (int)(t >> 6);
    int l    = (int)(t & 63);
    if (node >= N_NODES) return;
    const unsigned int* tab = (const unsigned int*)xwb;   // row = 64 uints
    const int beg = row_start[node];
    const int cnt = indeg[node];
    float ax = 0.f, ay = 0.f;
    int j = 0;
    #pragma unroll 1
    for (; j + 4 <= cnt; j += 4) {
        int s0 = csr_src[beg + j + 0];
        int s1 = csr_src[beg + j + 1];
        int s2 = csr_src[beg + j + 2];
        int s3 = csr_src[beg + j + 3];
        unsigned int u0 = tab[(size_t)s0 * 64 + l];
        unsigned int u1 = tab[(size_t)s1 * 64 + l];
        unsigned int u2 = tab[(size_t)s2 * 64 + l];
        unsigned int u3 = tab[(size_t)s3 * 64 + l];
        ax += __uint_as_float(u0 << 16) + __uint_as_float(u1 << 16)
            + __uint_as_float(u2 << 16) + __uint_as_float(u3 << 16);
        ay += __uint_as_float(u0 & 0xFFFF0000u) + __uint_as_float(u1 & 0xFFFF0000u)
            + __uint_as_float(u2 & 0xFFFF0000u) + __uint_as_float(u3 & 0xFFFF0000u);
    }
    for (; j < cnt; ++j) {
        unsigned int u = tab[(size_t)csr_src[beg + j] * 64 + l];
        ax += __uint_as_float(u << 16);
        ay += __uint_as_float(u & 0xFFFF0000u);
    }
    // self loop (already carries one dinv factor)
    {
        unsigned int u = tab[(size_t)node * 64 + l];
        ax += __uint_as_float(u << 16);
        ay += __uint_as_float(u & 0xFFFF0000u);
    }
    float dv = dinv[node];
    float rx = ax * dv + b[l * 2];
    float ry = ay * dv + b[l * 2 + 1];
    if (do_relu) { rx = fmaxf(rx, 0.f); ry = fmaxf(ry, 0.f); }
    if (OUT_BF16) {
        unsigned int o = (unsigned int)f2bf(rx) | ((unsigned int)f2bf(ry) << 16);
        ((unsigned int*)outv)[(size_t)node * 64 + l] = o;
    } else {
        ((float2*)outv)[(size_t)node * 64 + l] = make_float2(rx, ry);
    }
}

// ---------------- per-graph node count ----------------
__global__ void k_count(const int* __restrict__ batch, float* __restrict__ gcnt) {
    int i = blockIdx.x * blockDim.x + threadIdx.x;
    if (i < N_NODES) atomicAdd(&gcnt[batch[i]], 1.0f);
}

// ---------------- fused (h2 . Wlin) + segment-sum ----------------
__global__ __launch_bounds__(256) void k_pool(const float* __restrict__ h2,
                                               const int* __restrict__ batch,
                                               const float* __restrict__ Wlin,
                                               float* __restrict__ gsum) {
    long long t = (long long)blockIdx.x * blockDim.x + threadIdx.x;
    int node = (int)(t >> 6);
    int l    = (int)(t & 63);
    if (node >= N_NODES) return;
    const float* hp = h2 + (size_t)node * NFEAT;
    float p = hp[l] * Wlin[l] + hp[64 + l] * Wlin[64 + l];
    for (int off = 32; off > 0; off >>= 1) p += __shfl_down(p, off);
    if (l == 0) atomicAdd(&gsum[batch[node]], p);
}

__global__ void k_final(const float* __restrict__ gsum, const float* __restrict__ gcnt,
                        const float* __restrict__ blin, float* __restrict__ out) {
    int g = blockIdx.x * blockDim.x + threadIdx.x;
    if (g < NGRAPHS) out[g] = gsum[g] / fmaxf(gcnt[g], 1.0f) + blin[0];
}

extern "C" void kernel_launch(void* const* d_in, const int* in_sizes, int n_in,
                              void* d_out, int out_size, void* d_ws, size_t ws_size,
                              hipStream_t stream) {
    const float* x    = (const float*)d_in[0];
    const int*   ei   = (const int*)d_in[1];
    const int*   bat  = (const int*)d_in[2];
    const float* W1   = (const float*)d_in[3];
    const float* b1   = (const float*)d_in[4];
    const float* W2   = (const float*)d_in[5];
    const float* b2   = (const float*)d_in[6];
    const float* Wlin = (const float*)d_in[7];
    const float* blin = (const float*)d_in[8];
    float* out = (float*)d_out;

    const int* src = ei;
    const int* dst = ei + N_EDGES;

    // ---- workspace layout ----
    const size_t NF = (size_t)N_NODES * NFEAT;
    float* h2 = (float*)d_ws;                              // [N,128] fp32
    unsigned short* bufA = (unsigned short*)(h2 + NF);     // bf16 table A
    unsigned short* bufB = bufA + NF;                      // bf16 table B (h1)
    float* dinv = (float*)(bufB + NF);                     // [N]
    float* gsum = dinv + N_NODES;                          // [G]  } zeroed together
    float* gcnt = gsum + NGRAPHS;                          // [G]  }
    int* indeg     = (int*)(gcnt + NGRAPHS);               // [N]  }
    int* cursor    = indeg + N_NODES;                      // [N]  }
    int* row_start = cursor + N_NODES;                     // [N]
    int* bsum      = row_start + N_NODES;                  // [128]
    unsigned short* WT1 = (unsigned short*)(bsum + 128);   // [128*128] bf16 W1^T
    unsigned short* WT2 = WT1 + 128 * 128;                 // [128*128] bf16 W2^T
    int* csr_src   = (int*)(WT2 + 128 * 128);              // [E]

    const int BS = 256;
    const int nb_scan = (N_NODES + SCAN_CHUNK - 1) / SCAN_CHUNK;
    int node_blocks = (N_NODES + BS - 1) / BS;
    int edge_blocks = (N_EDGES + BS - 1) / BS;
    int wave_blocks = (int)(((long long)N_NODES * 64 + BS - 1) / BS);
    int gemm_blocks = (N_NODES + 127) / 128;

    // ---- zero accumulators (gsum,gcnt,indeg,cursor contiguous) ----
    hipMemsetAsync(gsum, 0, (2 * NGRAPHS) * sizeof(float) + (2 * N_NODES) * sizeof(int), stream);

    // ---- degree, norms, CSR, W prep ----
    k_hist<<<edge_blocks, BS, 0, stream>>>(dst, indeg);
    k_dinv<<<node_blocks, BS, 0, stream>>>(indeg, dinv);
    k_scan1<<<nb_scan, BS, 0, stream>>>(indeg, row_start, bsum, N_NODES);
    k_scan2<<<1, 128, 0, stream>>>(bsum, nb_scan);
    k_scan3<<<node_blocks, BS, 0, stream>>>(row_start, bsum, N_NODES);
    k_csr<<<edge_blocks, BS, 0, stream>>>(src, dst, row_start, cursor, csr_src);
    k_prepw<<<2, BS, 0, stream>>>(W1, W2, WT1, WT2);

    // ---- layer 1 ----
    k_gemm_mfma<false><<<gemm_blocks, BS, 0, stream>>>(x, WT1, dinv, bufA, N_NODES);
    k_gather<true><<<wave_blocks, BS, 0, stream>>>(bufA, csr_src, row_start, indeg, dinv, b1, bufB, 1);

    // ---- layer 2 ----
    k_gemm_mfma<true><<<gemm_blocks, BS, 0, stream>>>(bufB, WT2, dinv, bufA, N_NODES);
    k_gather<false><<<wave_blocks, BS, 0, stream>>>(bufA, csr_src, row_start, indeg, dinv, b2, h2, 0);

    // ---- pool + linear ----
    k_count<<<node_blocks, BS, 0, stream>>>(bat, gcnt);
    k_pool<<<wave_blocks, BS, 0, stream>>>(h2, bat, Wlin, gsum);
    k_final<<<(NGRAPHS + BS - 1) / BS, BS, 0, stream>>>(gsum, gcnt, blin, out);
}